// Round 7
// baseline (832.273 us; speedup 1.0000x reference)
//
#include <hip/hip_runtime.h>

typedef unsigned short u16;
typedef __attribute__((ext_vector_type(8))) short short8;
typedef __attribute__((ext_vector_type(8))) __bf16 bf16x8;
typedef __attribute__((ext_vector_type(4))) float f32x4;

#define DEV __device__ __forceinline__

DEV float bf2f(u16 u) {
    union { unsigned v; float f; } x; x.v = ((unsigned)u) << 16; return x.f;
}
DEV u16 f2bf(float f) {
    union { float f; unsigned v; } x; x.f = f;
    unsigned r = x.v + 0x7fff + ((x.v >> 16) & 1);
    return (u16)(r >> 16);
}

DEV f32x4 mfma16(short8 a, short8 b, f32x4 c) {
    return __builtin_amdgcn_mfma_f32_16x16x32_bf16(
        __builtin_bit_cast(bf16x8, a), __builtin_bit_cast(bf16x8, b), c, 0, 0, 0);
}

typedef const __attribute__((address_space(1))) void* gas_ptr;
typedef __attribute__((address_space(3))) void* las_ptr;

// ---------------- Transpose: f32 [R][C] -> bf16 [C][R] ----------------
__global__ __launch_bounds__(256) void transpose_kernel(
    const float* __restrict__ in, u16* __restrict__ out, int R, int C)
{
    __shared__ u16 t[64][65];
    int tid = threadIdx.x;
    int bc = blockIdx.x * 64, br = blockIdx.y * 64;
    int r = tid >> 2, cs = (tid & 3) * 16;
    const float* ip = in + (size_t)(br + r) * C + bc + cs;
    f32x4 v0 = *(const f32x4*)ip, v1 = *(const f32x4*)(ip + 4),
          v2 = *(const f32x4*)(ip + 8), v3 = *(const f32x4*)(ip + 12);
#pragma unroll
    for (int j = 0; j < 4; j++) {
        t[r][cs + j]      = f2bf(v0[j]);
        t[r][cs + 4 + j]  = f2bf(v1[j]);
        t[r][cs + 8 + j]  = f2bf(v2[j]);
        t[r][cs + 12 + j] = f2bf(v3[j]);
    }
    __syncthreads();
    int n = tid >> 2, ks = (tid & 3) * 16;
    short8 o0, o1;
#pragma unroll
    for (int j = 0; j < 8; j++) { o0[j] = (short)t[ks + j][n]; o1[j] = (short)t[ks + 8 + j][n]; }
    u16* op = out + (size_t)(bc + n) * R + br + ks;
    *(short8*)op = o0;
    *(short8*)(op + 8) = o1;
}

// ---------------- LayerNorm ----------------
template<int INBF>
__global__ __launch_bounds__(256) void ln_kernel(
    const void* __restrict__ xp, const float* __restrict__ sc, const float* __restrict__ sh,
    u16* __restrict__ out)
{
    int row = blockIdx.x, tid = threadIdx.x;
    float f[8], sum = 0.f, ss = 0.f;
    if (INBF) {
        short8 v = *(const short8*)((const u16*)xp + (size_t)row * 2048 + tid * 8);
#pragma unroll
        for (int j = 0; j < 8; j++) f[j] = bf2f((u16)v[j]);
    } else {
        const f32x4* xr = (const f32x4*)((const float*)xp + (size_t)row * 2048 + tid * 8);
        f32x4 a = xr[0], b = xr[1];
#pragma unroll
        for (int j = 0; j < 4; j++) { f[j] = a[j]; f[4 + j] = b[j]; }
    }
#pragma unroll
    for (int j = 0; j < 8; j++) { sum += f[j]; ss += f[j] * f[j]; }
#pragma unroll
    for (int m = 1; m < 64; m <<= 1) { sum += __shfl_xor(sum, m, 64); ss += __shfl_xor(ss, m, 64); }
    __shared__ float red[8];
    int w = tid >> 6, l = tid & 63;
    if (l == 0) { red[w] = sum; red[4 + w] = ss; }
    __syncthreads();
    sum = red[0] + red[1] + red[2] + red[3];
    ss  = red[4] + red[5] + red[6] + red[7];
    float mean = sum * (1.f / 2048.f);
    float var  = ss * (1.f / 2048.f) - mean * mean;
    float rstd = rsqrtf(var + 1e-5f);
    const f32x4* sp = (const f32x4*)(sc + tid * 8);
    const f32x4* bp = (const f32x4*)(sh + tid * 8);
    f32x4 s0 = sp[0], s1 = sp[1], b0 = bp[0], b1 = bp[1];
    short8 o;
#pragma unroll
    for (int j = 0; j < 4; j++) {
        o[j]     = (short)f2bf((f[j] - mean) * rstd * s0[j] + b0[j]);
        o[4 + j] = (short)f2bf((f[4 + j] - mean) * rstd * s1[j] + b1[j]);
    }
    *(short8*)(out + (size_t)row * 2048 + tid * 8) = o;
}

// ---- swizzled chunk staging: one operand K-tile (ROWS x 32 bf16) into LDS ----
// chunk (16B) ci: r = ci>>2, lds chunk col chp = ci&3 holds global chunk ch = chp ^ ((r>>1)&3)
template<int ROWS>
DEV void stage_op(const u16* __restrict__ G, int ldK, int t, u16* lds_op, int tid)
{
#pragma unroll
    for (int c2 = 0; c2 < ROWS / 128; c2++) {
        int ci = c2 * 512 + tid;
        int r = ci >> 2, chp = ci & 3;
        int ch = chp ^ ((r >> 1) & 3);
        const u16* g = G + (size_t)r * ldK + t * 32 + ch * 8;
        u16* d = lds_op + (c2 * 512 + (tid >> 6) * 64) * 8;
        __builtin_amdgcn_global_load_lds((gas_ptr)g, (las_ptr)d, 16, 0, 0);
    }
}

// swizzled fragment read: global (r, ch) lives at lds chunk (r, ch ^ ((r>>1)&3))
DEV short8 read_frag(const u16* lds_op, int r, int ch)
{
    int off = r * 32 + ((ch ^ ((r >> 1) & 3)) << 3);
    return *(const short8*)(lds_op + off);
}

// ---------------- Deep-pipelined GEMM: C(MxN) = A(MxK) * BT(NxK), bf16 ----------------
// BM tile x 256 N-tile, BK=32, 4-slot LDS ring, prefetch distance 3, counted vmcnt.
// 512 threads = 8 waves (2M x 4N). Per-wave (BM/2) x 64 output.
// EPI: 0 plain, 1 +bias+residual, 2 +bias+gelu ; OUTF: f32 out ; RESBF: residual bf16
// SPLITM: 0 normal; 1 QKV col>>11 split (ACT); 2 vT col>>11 split (2048x2048)
template<int BM, int EPI, int OUTF, int RESBF, int SPLITM>
__global__ __launch_bounds__(512, 2) void gemm8(
    const u16* __restrict__ A, const u16* __restrict__ BT, void* __restrict__ Cp,
    const float* __restrict__ bias, const void* __restrict__ res, int M, int N, int K)
{
    constexpr int MI = BM / 32;            // A-frags per wave
    constexpr int LPG = (BM == 256) ? 4 : 3; // gload_lds instrs per wave per group
    __shared__ u16 As[4][BM * 32];
    __shared__ u16 Bs[4][256 * 32];

    int tid = threadIdx.x, l = tid & 63, w = tid >> 6;
    int wm = w >> 2, wn = w & 3;

    // bijective XCD swizzle; consecutive wg share bx (B-panel) for L2 locality
    int nbx = gridDim.x, nby = gridDim.y;
    int nwg = nbx * nby;
    int orig = blockIdx.y * nbx + blockIdx.x;
    int wg = (orig & 7) * (nwg >> 3) + (orig >> 3);
    int bx = wg / nby, by = wg % nby;

    int mbase = by * BM, nbase = bx * 256;
    const u16* Ag = A + (size_t)mbase * K;
    const u16* Bg = BT + (size_t)nbase * K;
    int NT = K >> 5;

    // prologue: stage tiles 0,1,2
#pragma unroll
    for (int t0 = 0; t0 < 3; t0++) {
        stage_op<BM>(Ag, K, t0, As[t0], tid);
        stage_op<256>(Bg, K, t0, Bs[t0], tid);
    }
    if constexpr (LPG == 4) asm volatile("s_waitcnt vmcnt(8)" ::: "memory");
    else                    asm volatile("s_waitcnt vmcnt(6)" ::: "memory");
    __builtin_amdgcn_sched_barrier(0);
    __builtin_amdgcn_s_barrier();
    __builtin_amdgcn_sched_barrier(0);

    f32x4 acc[MI][4];
#pragma unroll
    for (int i = 0; i < MI; i++)
#pragma unroll
        for (int j = 0; j < 4; j++) acc[i][j] = (f32x4){0.f, 0.f, 0.f, 0.f};

    for (int t = 0; t < NT; ++t) {
        int slot = t & 3;
        if (t + 3 < NT) {
            int ps = (t + 3) & 3;
            stage_op<BM>(Ag, K, t + 3, As[ps], tid);
            stage_op<256>(Bg, K, t + 3, Bs[ps], tid);
        }
        short8 af[MI], bf[4];
#pragma unroll
        for (int i = 0; i < MI; i++)
            af[i] = read_frag(As[slot], wm * (BM / 2) + i * 16 + (l & 15), l >> 4);
#pragma unroll
        for (int j = 0; j < 4; j++)
            bf[j] = read_frag(Bs[slot], wn * 64 + j * 16 + (l & 15), l >> 4);
        __builtin_amdgcn_s_setprio(1);
#pragma unroll
        for (int i = 0; i < MI; i++)
#pragma unroll
            for (int j = 0; j < 4; j++)
                acc[i][j] = mfma16(af[i], bf[j], acc[i][j]);
        __builtin_amdgcn_s_setprio(0);
        if (t < NT - 1) {
            if (t + 3 < NT) {
                if constexpr (LPG == 4) asm volatile("s_waitcnt vmcnt(8)" ::: "memory");
                else                    asm volatile("s_waitcnt vmcnt(6)" ::: "memory");
            } else if (t + 2 < NT) {
                if constexpr (LPG == 4) asm volatile("s_waitcnt vmcnt(4)" ::: "memory");
                else                    asm volatile("s_waitcnt vmcnt(3)" ::: "memory");
            } else {
                asm volatile("s_waitcnt vmcnt(0)" ::: "memory");
            }
            __builtin_amdgcn_sched_barrier(0);
            __builtin_amdgcn_s_barrier();
            __builtin_amdgcn_sched_barrier(0);
        }
    }

#pragma unroll
    for (int mi = 0; mi < MI; mi++) {
#pragma unroll
        for (int ni = 0; ni < 4; ni++) {
            int col = nbase + wn * 64 + ni * 16 + (l & 15);
            float bval = (EPI != 0) ? bias[col] : 0.f;
#pragma unroll
            for (int r = 0; r < 4; r++) {
                int row = mbase + wm * (BM / 2) + mi * 16 + (l >> 4) * 4 + r;
                float v = acc[mi][ni][r];
                if (EPI == 1) {
                    size_t ridx = (size_t)row * N + col;
                    float rv = RESBF ? bf2f(((const u16*)res)[ridx]) : ((const float*)res)[ridx];
                    v += bval + rv;
                }
                if (EPI == 2) {
                    v += bval;
                    float tt = tanhf(0.7978845608028654f * (v + 0.044715f * v * v * v));
                    v = 0.5f * v * (1.f + tt);
                }
                if (SPLITM == 1) {
                    ((u16*)Cp)[(size_t)(col >> 11) * 8388608ULL + (size_t)row * 2048 + (col & 2047)] = f2bf(v);
                } else if (SPLITM == 2) {
                    ((u16*)Cp)[(size_t)(col >> 11) * 4194304ULL + (size_t)row * 2048 + (col & 2047)] = f2bf(v);
                } else if (OUTF) {
                    ((float*)Cp)[(size_t)row * N + col] = v;
                } else {
                    ((u16*)Cp)[(size_t)row * N + col] = f2bf(v);
                }
            }
        }
    }
}

// ---------------- Causal flash attention: H=16, HD=128, S=2048 ----------------
// QBLK=128: 4 waves x 32 q-rows (2 m-groups of 16). KVBLK=64. Merged 64-key softmax.
// V pre-transposed in global: VTg[(b*16+h)*128 + d][key]
__global__ __launch_bounds__(256, 2) void attn_kernel(
    const u16* __restrict__ Q, const u16* __restrict__ Kp, const u16* __restrict__ VTg,
    u16* __restrict__ O)
{
    __shared__ u16 Ks[64 * 128];
    __shared__ u16 VT[128 * 64];
    __shared__ u16 Ps[4 * 2048];
    int tid = threadIdx.x, l = tid & 63, w = tid >> 6;
    int qtl = (int)gridDim.x - 1 - (int)blockIdx.x;
    int bh = blockIdx.y, b = bh >> 4, h = bh & 15;
    const float SCALE = 0.08838834764831845f;
    int qbase = qtl * 128;
    size_t bS = (size_t)b * 2048;
    const u16* vrow = VTg + (size_t)bh * 128 * 2048;

    short8 qf[2][4];
#pragma unroll
    for (int mg = 0; mg < 2; mg++) {
        int qrow = qbase + w * 32 + mg * 16 + (l & 15);
        const u16* qp = Q + (bS + qrow) * 2048 + h * 128 + (l >> 4) * 8;
#pragma unroll
        for (int ds = 0; ds < 4; ds++) qf[mg][ds] = *(const short8*)(qp + ds * 32);
    }
    float m_[2][4], l_[2][4];
    f32x4 o_[2][8];
#pragma unroll
    for (int mg = 0; mg < 2; mg++)
#pragma unroll
        for (int r = 0; r < 4; r++) { m_[mg][r] = -1e30f; l_[mg][r] = 0.f; }
#pragma unroll
    for (int mg = 0; mg < 2; mg++)
#pragma unroll
        for (int d = 0; d < 8; d++) o_[mg][d] = (f32x4){0.f, 0.f, 0.f, 0.f};

    int ktmax = 2 * qtl + 1;
    for (int kt = 0; kt <= ktmax; ++kt) {
        int kbase = kt * 64;
#pragma unroll
        for (int it = 0; it < 4; ++it) {
            int slot = it * 256 + tid;
            int key = slot >> 4, dseg = slot & 15;
            short8 kv = *(const short8*)(Kp + (bS + kbase + key) * 2048 + h * 128 + dseg * 8);
            int kidx = ((key * 256 + dseg * 16) ^ ((key & 7) << 4)) >> 1;
            *(short8*)&Ks[kidx] = kv;
            int d = slot >> 3, k8 = slot & 7;
            short8 vv = *(const short8*)(vrow + (size_t)d * 2048 + kbase + k8 * 8);
            int vidx = ((d * 128 + k8 * 16) ^ ((d & 7) << 4)) >> 1;
            *(short8*)&VT[vidx] = vv;
        }
        __syncthreads();

        f32x4 s[2][4];
#pragma unroll
        for (int mg = 0; mg < 2; mg++)
#pragma unroll
            for (int kg = 0; kg < 4; kg++) s[mg][kg] = (f32x4){0.f, 0.f, 0.f, 0.f};
        __builtin_amdgcn_s_setprio(1);
#pragma unroll
        for (int kg = 0; kg < 4; kg++) {
            int key0 = kg * 16 + (l & 15);
#pragma unroll
            for (int ds = 0; ds < 4; ds++) {
                int i0 = ((key0 * 256 + ds * 64 + (l >> 4) * 16) ^ ((key0 & 7) << 4)) >> 1;
                short8 kb = *(const short8*)&Ks[i0];
                s[0][kg] = mfma16(qf[0][ds], kb, s[0][kg]);
                s[1][kg] = mfma16(qf[1][ds], kb, s[1][kg]);
            }
        }
        __builtin_amdgcn_s_setprio(0);

        bool domask = (kbase + 63) > qbase;
        float alpha[2][4];
        u16* Pw = &Ps[w * 2048];
#pragma unroll
        for (int mg = 0; mg < 2; mg++) {
#pragma unroll
            for (int r = 0; r < 4; r++) {
                int qrow = qbase + w * 32 + mg * 16 + (l >> 4) * 4 + r;
                float aa[4];
#pragma unroll
                for (int kg = 0; kg < 4; kg++) {
                    float a = s[mg][kg][r] * SCALE;
                    if (domask && (kbase + kg * 16 + (l & 15)) > qrow) a = -1e30f;
                    aa[kg] = a;
                }
                float mx = fmaxf(fmaxf(aa[0], aa[1]), fmaxf(aa[2], aa[3]));
                mx = fmaxf(mx, __shfl_xor(mx, 1, 64));
                mx = fmaxf(mx, __shfl_xor(mx, 2, 64));
                mx = fmaxf(mx, __shfl_xor(mx, 4, 64));
                mx = fmaxf(mx, __shfl_xor(mx, 8, 64));
                float mn = fmaxf(m_[mg][r], mx);
                float al = __expf(m_[mg][r] - mn);
                m_[mg][r] = mn;
                float p[4], rs = 0.f;
#pragma unroll
                for (int kg = 0; kg < 4; kg++) { p[kg] = __expf(aa[kg] - mn); rs += p[kg]; }
                rs += __shfl_xor(rs, 1, 64);
                rs += __shfl_xor(rs, 2, 64);
                rs += __shfl_xor(rs, 4, 64);
                rs += __shfl_xor(rs, 8, 64);
                l_[mg][r] = l_[mg][r] * al + rs;
                alpha[mg][r] = al;
#pragma unroll
                for (int kg = 0; kg < 4; kg++) {
                    int col = kg * 16 + (l & 15);
                    int lp = ((l >> 4) * 4 + r) | (((col >> 3) & 3) << 4);
                    Pw[(mg * 2 + (col >> 5)) * 512 + lp * 8 + (col & 7)] = f2bf(p[kg]);
                }
            }
        }
#pragma unroll
        for (int mg = 0; mg < 2; mg++)
#pragma unroll
            for (int dblk = 0; dblk < 8; dblk++)
#pragma unroll
                for (int r = 0; r < 4; r++) o_[mg][dblk][r] *= alpha[mg][r];

        __builtin_amdgcn_s_setprio(1);
#pragma unroll
        for (int kk = 0; kk < 2; kk++) {
            short8 pa0 = *(const short8*)&Pw[(0 * 2 + kk) * 512 + l * 8];
            short8 pa1 = *(const short8*)&Pw[(1 * 2 + kk) * 512 + l * 8];
#pragma unroll
            for (int dblk = 0; dblk < 8; dblk++) {
                int d = dblk * 16 + (l & 15);
                int iv = ((d * 128 + kk * 64 + (l >> 4) * 16) ^ ((d & 7) << 4)) >> 1;
                short8 vb = *(const short8*)&VT[iv];
                o_[0][dblk] = mfma16(pa0, vb, o_[0][dblk]);
                o_[1][dblk] = mfma16(pa1, vb, o_[1][dblk]);
            }
        }
        __builtin_amdgcn_s_setprio(0);
        __syncthreads();
    }

#pragma unroll
    for (int mg = 0; mg < 2; mg++) {
#pragma unroll
        for (int dblk = 0; dblk < 8; dblk++) {
#pragma unroll
            for (int r = 0; r < 4; r++) {
                int qrow = qbase + w * 32 + mg * 16 + (l >> 4) * 4 + r;
                float v = o_[mg][dblk][r] / l_[mg][r];
                O[(bS + qrow) * 2048 + h * 128 + dblk * 16 + (l & 15)] = f2bf(v);
            }
        }
    }
}

extern "C" void kernel_launch(void* const* d_in, const int* in_sizes, int n_in,
                              void* d_out, int out_size, void* d_ws, size_t ws_size,
                              hipStream_t stream)
{
    const float* x    = (const float*)d_in[0];
    const float* ln1s = (const float*)d_in[1];
    const float* ln1b = (const float*)d_in[2];
    const float* Wq   = (const float*)d_in[3];
    const float* Wk   = (const float*)d_in[4];
    const float* Wv   = (const float*)d_in[5];
    const float* Wo   = (const float*)d_in[6];
    const float* bo   = (const float*)d_in[7];
    const float* ln2s = (const float*)d_in[8];
    const float* ln2b = (const float*)d_in[9];
    const float* W1   = (const float*)d_in[10];
    const float* b1   = (const float*)d_in[11];
    const float* W2   = (const float*)d_in[12];
    const float* b2   = (const float*)d_in[13];
    float* out = (float*)d_out;
    const size_t ACT = 8388608ULL;

    u16* ws16 = (u16*)d_ws;
    u16* xn   = ws16;
    u16* q    = ws16 + ACT;
    u16* k    = ws16 + 2 * ACT;
    u16* vT   = ws16 + 3 * ACT;
    u16* hbuf = ws16 + 2 * ACT;
    u16* wt   = ws16 + 6 * ACT;
    u16* x2   = q;
    (void)k;

    dim3 blk(256), blk8(512);
    transpose_kernel<<<dim3(32, 32), blk, 0, stream>>>(Wq, wt,                  2048, 2048);
    transpose_kernel<<<dim3(32, 32), blk, 0, stream>>>(Wk, wt + (ACT >> 1),     2048, 2048);
    transpose_kernel<<<dim3(32, 32), blk, 0, stream>>>(Wv, wt + ACT,            2048, 2048);
    transpose_kernel<<<dim3(32, 32), blk, 0, stream>>>(Wo, wt + 3 * (ACT >> 1), 2048, 2048);
    ln_kernel<0><<<4096, blk, 0, stream>>>(x, ln1s, ln1b, xn);
    // fused QK: BT = [WqT;WkT] -> q, k buffers
    gemm8<256, 0, 0, 0, 1><<<dim3(16, 16), blk8, 0, stream>>>(xn, wt, q, nullptr, nullptr, 4096, 4096, 2048);
    // vT = WvT * xn^T -> vT[b][d][s]
    gemm8<128, 0, 0, 0, 2><<<dim3(16, 16), blk8, 0, stream>>>(wt + ACT, xn, vT, nullptr, nullptr, 2048, 4096, 2048);
    attn_kernel<<<dim3(16, 32), blk, 0, stream>>>(q, k, vT, xn); // ctx -> xn
    gemm8<128, 1, 0, 0, 0><<<dim3(8, 32), blk8, 0, stream>>>(xn, wt + 3 * (ACT >> 1), x2, bo, x, 4096, 2048, 2048);
    transpose_kernel<<<dim3(128, 32), blk, 0, stream>>>(W1, wt, 2048, 8192);
    ln_kernel<1><<<4096, blk, 0, stream>>>(x2, ln2s, ln2b, xn);
    gemm8<256, 2, 0, 0, 0><<<dim3(32, 16), blk8, 0, stream>>>(xn, wt, hbuf, b1, nullptr, 4096, 8192, 2048);
    transpose_kernel<<<dim3(32, 128), blk, 0, stream>>>(W2, wt, 8192, 2048);
    gemm8<128, 1, 1, 1, 0><<<dim3(8, 32), blk8, 0, stream>>>(hbuf, wt, out, b2, x2, 4096, 2048, 8192);
}

// Round 8
// 783.260 us; speedup vs baseline: 1.0626x; 1.0626x over previous
//
#include <hip/hip_runtime.h>

typedef unsigned short u16;
typedef __attribute__((ext_vector_type(8))) short short8;
typedef __attribute__((ext_vector_type(8))) __bf16 bf16x8;
typedef __attribute__((ext_vector_type(4))) float f32x4;

#define DEV __device__ __forceinline__

DEV float bf2f(u16 u) {
    union { unsigned v; float f; } x; x.v = ((unsigned)u) << 16; return x.f;
}
DEV u16 f2bf(float f) {
    union { float f; unsigned v; } x; x.f = f;
    unsigned r = x.v + 0x7fff + ((x.v >> 16) & 1);
    return (u16)(r >> 16);
}

DEV f32x4 mfma16(short8 a, short8 b, f32x4 c) {
    return __builtin_amdgcn_mfma_f32_16x16x32_bf16(
        __builtin_bit_cast(bf16x8, a), __builtin_bit_cast(bf16x8, b), c, 0, 0, 0);
}

typedef const __attribute__((address_space(1))) void* gas_ptr;
typedef __attribute__((address_space(3))) void* las_ptr;

// ---------------- Transpose: f32 [R][C] -> bf16 [C][R] ----------------
__global__ __launch_bounds__(256) void transpose_kernel(
    const float* __restrict__ in, u16* __restrict__ out, int R, int C)
{
    __shared__ u16 t[64][65];
    int tid = threadIdx.x;
    int bc = blockIdx.x * 64, br = blockIdx.y * 64;
    int r = tid >> 2, cs = (tid & 3) * 16;
    const float* ip = in + (size_t)(br + r) * C + bc + cs;
    f32x4 v0 = *(const f32x4*)ip, v1 = *(const f32x4*)(ip + 4),
          v2 = *(const f32x4*)(ip + 8), v3 = *(const f32x4*)(ip + 12);
#pragma unroll
    for (int j = 0; j < 4; j++) {
        t[r][cs + j]      = f2bf(v0[j]);
        t[r][cs + 4 + j]  = f2bf(v1[j]);
        t[r][cs + 8 + j]  = f2bf(v2[j]);
        t[r][cs + 12 + j] = f2bf(v3[j]);
    }
    __syncthreads();
    int n = tid >> 2, ks = (tid & 3) * 16;
    short8 o0, o1;
#pragma unroll
    for (int j = 0; j < 8; j++) { o0[j] = (short)t[ks + j][n]; o1[j] = (short)t[ks + 8 + j][n]; }
    u16* op = out + (size_t)(bc + n) * R + br + ks;
    *(short8*)op = o0;
    *(short8*)(op + 8) = o1;
}

// ---------------- LayerNorm ----------------
template<int INBF>
__global__ __launch_bounds__(256) void ln_kernel(
    const void* __restrict__ xp, const float* __restrict__ sc, const float* __restrict__ sh,
    u16* __restrict__ out)
{
    int row = blockIdx.x, tid = threadIdx.x;
    float f[8], sum = 0.f, ss = 0.f;
    if (INBF) {
        short8 v = *(const short8*)((const u16*)xp + (size_t)row * 2048 + tid * 8);
#pragma unroll
        for (int j = 0; j < 8; j++) f[j] = bf2f((u16)v[j]);
    } else {
        const f32x4* xr = (const f32x4*)((const float*)xp + (size_t)row * 2048 + tid * 8);
        f32x4 a = xr[0], b = xr[1];
#pragma unroll
        for (int j = 0; j < 4; j++) { f[j] = a[j]; f[4 + j] = b[j]; }
    }
#pragma unroll
    for (int j = 0; j < 8; j++) { sum += f[j]; ss += f[j] * f[j]; }
#pragma unroll
    for (int m = 1; m < 64; m <<= 1) { sum += __shfl_xor(sum, m, 64); ss += __shfl_xor(ss, m, 64); }
    __shared__ float red[8];
    int w = tid >> 6, l = tid & 63;
    if (l == 0) { red[w] = sum; red[4 + w] = ss; }
    __syncthreads();
    sum = red[0] + red[1] + red[2] + red[3];
    ss  = red[4] + red[5] + red[6] + red[7];
    float mean = sum * (1.f / 2048.f);
    float var  = ss * (1.f / 2048.f) - mean * mean;
    float rstd = rsqrtf(var + 1e-5f);
    const f32x4* sp = (const f32x4*)(sc + tid * 8);
    const f32x4* bp = (const f32x4*)(sh + tid * 8);
    f32x4 s0 = sp[0], s1 = sp[1], b0 = bp[0], b1 = bp[1];
    short8 o;
#pragma unroll
    for (int j = 0; j < 4; j++) {
        o[j]     = (short)f2bf((f[j] - mean) * rstd * s0[j] + b0[j]);
        o[4 + j] = (short)f2bf((f[4 + j] - mean) * rstd * s1[j] + b1[j]);
    }
    *(short8*)(out + (size_t)row * 2048 + tid * 8) = o;
}

// ---------------- 3-slot-ring GEMM: C(MxN) = A(MxK) * BT(NxK), bf16 ----------------
// BM=256 x BN=128, BK=64, 512 thr = 8 waves (4M x 2N), per-wave 64x64.
// LDS 144KB: As[3][256][64], Bs[3][128][64], row-chunk XOR swizzle ch^(r&7).
// Counted vmcnt(6) (tile u+2 in flight), one barrier per K-tile.
// EPI: 0 plain, 1 +bias+residual, 2 +bias+gelu ; OUTF f32 out ; RESBF residual bf16
// SPLITM: 0 normal; 1 col>>11 split into ACT buffers; 2 col>>11 split into 2048x2048
template<int EPI, int OUTF, int RESBF, int SPLITM>
__global__ __launch_bounds__(512, 2) void gemm3r(
    const u16* __restrict__ A, const u16* __restrict__ BT, void* __restrict__ Cp,
    const float* __restrict__ bias, const void* __restrict__ res, int M, int N, int K)
{
    __shared__ u16 As[3][256 * 64];
    __shared__ u16 Bs[3][128 * 64];
    int tid = threadIdx.x, l = tid & 63, w = tid >> 6;
    int wm = w >> 1, wn = w & 1;

    // bijective XCD swizzle (all grids have nwg % 8 == 0)
    int nbx = gridDim.x, nby = gridDim.y;
    int nwg = nbx * nby;
    int orig = blockIdx.y * nbx + blockIdx.x;
    int wg = (orig & 7) * (nwg >> 3) + (orig >> 3);
    int bx = wg / nby, by = wg % nby;

    int mbase = by * 256, nbase = bx * 128;
    const u16* Ag = A + (size_t)mbase * K;
    const u16* Bg = BT + (size_t)nbase * K;
    int NT = K >> 6;

    auto stage = [&](int s, int u) {
#pragma unroll
        for (int g = 0; g < 4; g++) {
            int ci = g * 512 + tid;
            int r = ci >> 3, ch = (ci & 7) ^ (r & 7);
            const u16* gp = Ag + (size_t)r * K + u * 64 + ch * 8;
            __builtin_amdgcn_global_load_lds((gas_ptr)gp, (las_ptr)&As[s][(g * 512 + w * 64) * 8], 16, 0, 0);
        }
#pragma unroll
        for (int g = 0; g < 2; g++) {
            int ci = g * 512 + tid;
            int r = ci >> 3, ch = (ci & 7) ^ (r & 7);
            const u16* gp = Bg + (size_t)r * K + u * 64 + ch * 8;
            __builtin_amdgcn_global_load_lds((gas_ptr)gp, (las_ptr)&Bs[s][(g * 512 + w * 64) * 8], 16, 0, 0);
        }
    };

    f32x4 acc[4][4];
#pragma unroll
    for (int i = 0; i < 4; i++)
#pragma unroll
        for (int j = 0; j < 4; j++) acc[i][j] = (f32x4){0.f, 0.f, 0.f, 0.f};

    // prologue: stage tiles 0,1 ; wait tile0 (6 newest = tile1 may fly)
    stage(0, 0);
    stage(1, 1);
    asm volatile("s_waitcnt vmcnt(6)" ::: "memory");
    __builtin_amdgcn_sched_barrier(0);
    __builtin_amdgcn_s_barrier();
    __builtin_amdgcn_sched_barrier(0);

    int s0 = 0, s1 = 1, s2 = 2;
    for (int u = 0; u < NT; ++u) {
        if (u + 2 < NT) stage(s2, u + 2);
        const u16* Abase = &As[s0][0];
        const u16* Bbase = &Bs[s0][0];
        short8 a0[4], b0[4], a1[4], b1[4];
        int ra = wm * 64 + (l & 15);
        int rb = wn * 64 + (l & 15);
        int c0 = (l >> 4), c1 = 4 + (l >> 4);
#pragma unroll
        for (int i = 0; i < 4; i++) {
            int r = ra + i * 16;
            a0[i] = *(const short8*)&Abase[r * 64 + ((c0 ^ (r & 7)) << 3)];
        }
#pragma unroll
        for (int j = 0; j < 4; j++) {
            int r = rb + j * 16;
            b0[j] = *(const short8*)&Bbase[r * 64 + ((c0 ^ (r & 7)) << 3)];
        }
        asm volatile("s_waitcnt lgkmcnt(0)" ::: "memory");  // ks0 frags landed
        // issue ks1 reads before the MFMA cluster
#pragma unroll
        for (int i = 0; i < 4; i++) {
            int r = ra + i * 16;
            a1[i] = *(const short8*)&Abase[r * 64 + ((c1 ^ (r & 7)) << 3)];
        }
#pragma unroll
        for (int j = 0; j < 4; j++) {
            int r = rb + j * 16;
            b1[j] = *(const short8*)&Bbase[r * 64 + ((c1 ^ (r & 7)) << 3)];
        }
        __builtin_amdgcn_sched_barrier(0);
        __builtin_amdgcn_s_setprio(1);
#pragma unroll
        for (int i = 0; i < 4; i++)
#pragma unroll
            for (int j = 0; j < 4; j++)
                acc[i][j] = mfma16(a0[i], b0[j], acc[i][j]);
        __builtin_amdgcn_s_setprio(0);
        asm volatile("s_waitcnt lgkmcnt(0)" ::: "memory");  // ks1 frags landed
        __builtin_amdgcn_sched_barrier(0);
        __builtin_amdgcn_s_setprio(1);
#pragma unroll
        for (int i = 0; i < 4; i++)
#pragma unroll
            for (int j = 0; j < 4; j++)
                acc[i][j] = mfma16(a1[i], b1[j], acc[i][j]);
        __builtin_amdgcn_s_setprio(0);
        if (u < NT - 1) {
            if (u + 2 < NT) asm volatile("s_waitcnt vmcnt(6)" ::: "memory");
            else            asm volatile("s_waitcnt vmcnt(0)" ::: "memory");
            __builtin_amdgcn_sched_barrier(0);
            __builtin_amdgcn_s_barrier();
            __builtin_amdgcn_sched_barrier(0);
        }
        int t = s0; s0 = s1; s1 = s2; s2 = t;
    }

#pragma unroll
    for (int mi = 0; mi < 4; mi++) {
#pragma unroll
        for (int ni = 0; ni < 4; ni++) {
            int col = nbase + wn * 64 + ni * 16 + (l & 15);
            float bval = (EPI != 0) ? bias[col] : 0.f;
#pragma unroll
            for (int r = 0; r < 4; r++) {
                int row = mbase + wm * 64 + mi * 16 + (l >> 4) * 4 + r;
                float v = acc[mi][ni][r];
                if (EPI == 1) {
                    size_t ridx = (size_t)row * N + col;
                    float rv = RESBF ? bf2f(((const u16*)res)[ridx]) : ((const float*)res)[ridx];
                    v += bval + rv;
                }
                if (EPI == 2) {
                    v += bval;
                    float tt = tanhf(0.7978845608028654f * (v + 0.044715f * v * v * v));
                    v = 0.5f * v * (1.f + tt);
                }
                if (SPLITM == 1) {
                    ((u16*)Cp)[(size_t)(col >> 11) * 8388608ULL + (size_t)row * 2048 + (col & 2047)] = f2bf(v);
                } else if (SPLITM == 2) {
                    ((u16*)Cp)[(size_t)(col >> 11) * 4194304ULL + (size_t)row * 2048 + (col & 2047)] = f2bf(v);
                } else if (OUTF) {
                    ((float*)Cp)[(size_t)row * N + col] = v;
                } else {
                    ((u16*)Cp)[(size_t)row * N + col] = f2bf(v);
                }
            }
        }
    }
}

// ---------------- Causal flash attention: H=16, HD=128, S=2048 ----------------
// QBLK=128: 4 waves x 32 q-rows. KVBLK=64. V pre-transposed: VTg[(b*16+h)*128+d][key]
__global__ __launch_bounds__(256, 2) void attn_kernel(
    const u16* __restrict__ Q, const u16* __restrict__ Kp, const u16* __restrict__ VTg,
    u16* __restrict__ O)
{
    __shared__ u16 Ks[64 * 128];
    __shared__ u16 VT[128 * 64];
    __shared__ u16 Ps[4 * 2048];
    int tid = threadIdx.x, l = tid & 63, w = tid >> 6;
    int qtl = (int)gridDim.x - 1 - (int)blockIdx.x;
    int bh = blockIdx.y, b = bh >> 4, h = bh & 15;
    const float SCALE = 0.08838834764831845f;
    int qbase = qtl * 128;
    size_t bS = (size_t)b * 2048;
    const u16* vrow = VTg + (size_t)bh * 128 * 2048;

    short8 qf[2][4];
#pragma unroll
    for (int mg = 0; mg < 2; mg++) {
        int qrow = qbase + w * 32 + mg * 16 + (l & 15);
        const u16* qp = Q + (bS + qrow) * 2048 + h * 128 + (l >> 4) * 8;
#pragma unroll
        for (int ds = 0; ds < 4; ds++) qf[mg][ds] = *(const short8*)(qp + ds * 32);
    }
    float m_[2][4], l_[2][4];
    f32x4 o_[2][8];
#pragma unroll
    for (int mg = 0; mg < 2; mg++)
#pragma unroll
        for (int r = 0; r < 4; r++) { m_[mg][r] = -1e30f; l_[mg][r] = 0.f; }
#pragma unroll
    for (int mg = 0; mg < 2; mg++)
#pragma unroll
        for (int d = 0; d < 8; d++) o_[mg][d] = (f32x4){0.f, 0.f, 0.f, 0.f};

    int ktmax = 2 * qtl + 1;
    for (int kt = 0; kt <= ktmax; ++kt) {
        int kbase = kt * 64;
#pragma unroll
        for (int it = 0; it < 4; ++it) {
            int slot = it * 256 + tid;
            int key = slot >> 4, dseg = slot & 15;
            short8 kv = *(const short8*)(Kp + (bS + kbase + key) * 2048 + h * 128 + dseg * 8);
            int kidx = ((key * 256 + dseg * 16) ^ ((key & 7) << 4)) >> 1;
            *(short8*)&Ks[kidx] = kv;
            int d = slot >> 3, k8 = slot & 7;
            short8 vv = *(const short8*)(vrow + (size_t)d * 2048 + kbase + k8 * 8);
            int vidx = ((d * 128 + k8 * 16) ^ ((d & 7) << 4)) >> 1;
            *(short8*)&VT[vidx] = vv;
        }
        __syncthreads();

        f32x4 s[2][4];
#pragma unroll
        for (int mg = 0; mg < 2; mg++)
#pragma unroll
            for (int kg = 0; kg < 4; kg++) s[mg][kg] = (f32x4){0.f, 0.f, 0.f, 0.f};
        __builtin_amdgcn_s_setprio(1);
#pragma unroll
        for (int kg = 0; kg < 4; kg++) {
            int key0 = kg * 16 + (l & 15);
#pragma unroll
            for (int ds = 0; ds < 4; ds++) {
                int i0 = ((key0 * 256 + ds * 64 + (l >> 4) * 16) ^ ((key0 & 7) << 4)) >> 1;
                short8 kb = *(const short8*)&Ks[i0];
                s[0][kg] = mfma16(qf[0][ds], kb, s[0][kg]);
                s[1][kg] = mfma16(qf[1][ds], kb, s[1][kg]);
            }
        }
        __builtin_amdgcn_s_setprio(0);

        bool domask = (kbase + 63) > qbase;
        float alpha[2][4];
        u16* Pw = &Ps[w * 2048];
#pragma unroll
        for (int mg = 0; mg < 2; mg++) {
#pragma unroll
            for (int r = 0; r < 4; r++) {
                int qrow = qbase + w * 32 + mg * 16 + (l >> 4) * 4 + r;
                float aa[4];
#pragma unroll
                for (int kg = 0; kg < 4; kg++) {
                    float a = s[mg][kg][r] * SCALE;
                    if (domask && (kbase + kg * 16 + (l & 15)) > qrow) a = -1e30f;
                    aa[kg] = a;
                }
                float mx = fmaxf(fmaxf(aa[0], aa[1]), fmaxf(aa[2], aa[3]));
                mx = fmaxf(mx, __shfl_xor(mx, 1, 64));
                mx = fmaxf(mx, __shfl_xor(mx, 2, 64));
                mx = fmaxf(mx, __shfl_xor(mx, 4, 64));
                mx = fmaxf(mx, __shfl_xor(mx, 8, 64));
                float mn = fmaxf(m_[mg][r], mx);
                float al = __expf(m_[mg][r] - mn);
                m_[mg][r] = mn;
                float p[4], rs = 0.f;
#pragma unroll
                for (int kg = 0; kg < 4; kg++) { p[kg] = __expf(aa[kg] - mn); rs += p[kg]; }
                rs += __shfl_xor(rs, 1, 64);
                rs += __shfl_xor(rs, 2, 64);
                rs += __shfl_xor(rs, 4, 64);
                rs += __shfl_xor(rs, 8, 64);
                l_[mg][r] = l_[mg][r] * al + rs;
                alpha[mg][r] = al;
#pragma unroll
                for (int kg = 0; kg < 4; kg++) {
                    int col = kg * 16 + (l & 15);
                    int lp = ((l >> 4) * 4 + r) | (((col >> 3) & 3) << 4);
                    Pw[(mg * 2 + (col >> 5)) * 512 + lp * 8 + (col & 7)] = f2bf(p[kg]);
                }
            }
        }
#pragma unroll
        for (int mg = 0; mg < 2; mg++)
#pragma unroll
            for (int dblk = 0; dblk < 8; dblk++)
#pragma unroll
                for (int r = 0; r < 4; r++) o_[mg][dblk][r] *= alpha[mg][r];

        __builtin_amdgcn_s_setprio(1);
#pragma unroll
        for (int kk = 0; kk < 2; kk++) {
            short8 pa0 = *(const short8*)&Pw[(0 * 2 + kk) * 512 + l * 8];
            short8 pa1 = *(const short8*)&Pw[(1 * 2 + kk) * 512 + l * 8];
#pragma unroll
            for (int dblk = 0; dblk < 8; dblk++) {
                int d = dblk * 16 + (l & 15);
                int iv = ((d * 128 + kk * 64 + (l >> 4) * 16) ^ ((d & 7) << 4)) >> 1;
                short8 vb = *(const short8*)&VT[iv];
                o_[0][dblk] = mfma16(pa0, vb, o_[0][dblk]);
                o_[1][dblk] = mfma16(pa1, vb, o_[1][dblk]);
            }
        }
        __builtin_amdgcn_s_setprio(0);
        __syncthreads();
    }

#pragma unroll
    for (int mg = 0; mg < 2; mg++) {
#pragma unroll
        for (int dblk = 0; dblk < 8; dblk++) {
#pragma unroll
            for (int r = 0; r < 4; r++) {
                int qrow = qbase + w * 32 + mg * 16 + (l >> 4) * 4 + r;
                float v = o_[mg][dblk][r] / l_[mg][r];
                O[(bS + qrow) * 2048 + h * 128 + dblk * 16 + (l & 15)] = f2bf(v);
            }
        }
    }
}

extern "C" void kernel_launch(void* const* d_in, const int* in_sizes, int n_in,
                              void* d_out, int out_size, void* d_ws, size_t ws_size,
                              hipStream_t stream)
{
    const float* x    = (const float*)d_in[0];
    const float* ln1s = (const float*)d_in[1];
    const float* ln1b = (const float*)d_in[2];
    const float* Wq   = (const float*)d_in[3];
    const float* Wk   = (const float*)d_in[4];
    const float* Wv   = (const float*)d_in[5];
    const float* Wo   = (const float*)d_in[6];
    const float* bo   = (const float*)d_in[7];
    const float* ln2s = (const float*)d_in[8];
    const float* ln2b = (const float*)d_in[9];
    const float* W1   = (const float*)d_in[10];
    const float* b1   = (const float*)d_in[11];
    const float* W2   = (const float*)d_in[12];
    const float* b2   = (const float*)d_in[13];
    float* out = (float*)d_out;
    const size_t ACT = 8388608ULL;

    u16* ws16 = (u16*)d_ws;
    u16* xn   = ws16;
    u16* q    = ws16 + ACT;
    u16* k    = ws16 + 2 * ACT;
    u16* vT   = ws16 + 3 * ACT;
    u16* hbuf = ws16 + 2 * ACT;
    u16* wt   = ws16 + 6 * ACT;
    u16* x2   = q;
    (void)k;

    dim3 blk(256), blk8(512);
    transpose_kernel<<<dim3(32, 32), blk, 0, stream>>>(Wq, wt,                  2048, 2048);
    transpose_kernel<<<dim3(32, 32), blk, 0, stream>>>(Wk, wt + (ACT >> 1),     2048, 2048);
    transpose_kernel<<<dim3(32, 32), blk, 0, stream>>>(Wv, wt + ACT,            2048, 2048);
    transpose_kernel<<<dim3(32, 32), blk, 0, stream>>>(Wo, wt + 3 * (ACT >> 1), 2048, 2048);
    ln_kernel<0><<<4096, blk, 0, stream>>>(x, ln1s, ln1b, xn);
    // fused QK: BT = [WqT;WkT] -> q, k buffers
    gemm3r<0, 0, 0, 1><<<dim3(32, 16), blk8, 0, stream>>>(xn, wt, q, nullptr, nullptr, 4096, 4096, 2048);
    // vT = WvT * xn^T -> vT[b][d][s]
    gemm3r<0, 0, 0, 2><<<dim3(32, 8), blk8, 0, stream>>>(wt + ACT, xn, vT, nullptr, nullptr, 2048, 4096, 2048);
    attn_kernel<<<dim3(16, 32), blk, 0, stream>>>(q, k, vT, xn); // ctx -> xn
    gemm3r<1, 0, 0, 0><<<dim3(16, 16), blk8, 0, stream>>>(xn, wt + 3 * (ACT >> 1), x2, bo, x, 4096, 2048, 2048);
    transpose_kernel<<<dim3(128, 32), blk, 0, stream>>>(W1, wt, 2048, 8192);
    ln_kernel<1><<<4096, blk, 0, stream>>>(x2, ln2s, ln2b, xn);
    gemm3r<2, 0, 0, 0><<<dim3(64, 16), blk8, 0, stream>>>(xn, wt, hbuf, b1, nullptr, 4096, 8192, 2048);
    transpose_kernel<<<dim3(32, 128), blk, 0, stream>>>(W2, wt, 8192, 2048);
    gemm3r<1, 1, 1, 0><<<dim3(16, 16), blk8, 0, stream>>>(hbuf, wt, out, b2, x2, 4096, 2048, 8192);
}

// Round 9
// 669.922 us; speedup vs baseline: 1.2423x; 1.1692x over previous
//
#include <hip/hip_runtime.h>

typedef unsigned short u16;
typedef __attribute__((ext_vector_type(8))) short short8;
typedef __attribute__((ext_vector_type(8))) __bf16 bf16x8;
typedef __attribute__((ext_vector_type(4))) float f32x4;

#define DEV __device__ __forceinline__

DEV float bf2f(u16 u) {
    union { unsigned v; float f; } x; x.v = ((unsigned)u) << 16; return x.f;
}
DEV u16 f2bf(float f) {
    union { float f; unsigned v; } x; x.f = f;
    unsigned r = x.v + 0x7fff + ((x.v >> 16) & 1);
    return (u16)(r >> 16);
}

DEV f32x4 mfma16(short8 a, short8 b, f32x4 c) {
    return __builtin_amdgcn_mfma_f32_16x16x32_bf16(
        __builtin_bit_cast(bf16x8, a), __builtin_bit_cast(bf16x8, b), c, 0, 0, 0);
}

typedef const __attribute__((address_space(1))) void* gas_ptr;
typedef __attribute__((address_space(3))) void* las_ptr;

// ---------------- Transpose: f32 [R][C] -> bf16 [C][R] ----------------
__global__ __launch_bounds__(256) void transpose_kernel(
    const float* __restrict__ in, u16* __restrict__ out, int R, int C)
{
    __shared__ u16 t[64][65];
    int tid = threadIdx.x;
    int bc = blockIdx.x * 64, br = blockIdx.y * 64;
    int r = tid >> 2, cs = (tid & 3) * 16;
    const float* ip = in + (size_t)(br + r) * C + bc + cs;
    f32x4 v0 = *(const f32x4*)ip, v1 = *(const f32x4*)(ip + 4),
          v2 = *(const f32x4*)(ip + 8), v3 = *(const f32x4*)(ip + 12);
#pragma unroll
    for (int j = 0; j < 4; j++) {
        t[r][cs + j]      = f2bf(v0[j]);
        t[r][cs + 4 + j]  = f2bf(v1[j]);
        t[r][cs + 8 + j]  = f2bf(v2[j]);
        t[r][cs + 12 + j] = f2bf(v3[j]);
    }
    __syncthreads();
    int n = tid >> 2, ks = (tid & 3) * 16;
    short8 o0, o1;
#pragma unroll
    for (int j = 0; j < 8; j++) { o0[j] = (short)t[ks + j][n]; o1[j] = (short)t[ks + 8 + j][n]; }
    u16* op = out + (size_t)(bc + n) * R + br + ks;
    *(short8*)op = o0;
    *(short8*)(op + 8) = o1;
}

// ---------------- LayerNorm ----------------
template<int INBF>
__global__ __launch_bounds__(256) void ln_kernel(
    const void* __restrict__ xp, const float* __restrict__ sc, const float* __restrict__ sh,
    u16* __restrict__ out)
{
    int row = blockIdx.x, tid = threadIdx.x;
    float f[8], sum = 0.f, ss = 0.f;
    if (INBF) {
        short8 v = *(const short8*)((const u16*)xp + (size_t)row * 2048 + tid * 8);
#pragma unroll
        for (int j = 0; j < 8; j++) f[j] = bf2f((u16)v[j]);
    } else {
        const f32x4* xr = (const f32x4*)((const float*)xp + (size_t)row * 2048 + tid * 8);
        f32x4 a = xr[0], b = xr[1];
#pragma unroll
        for (int j = 0; j < 4; j++) { f[j] = a[j]; f[4 + j] = b[j]; }
    }
#pragma unroll
    for (int j = 0; j < 8; j++) { sum += f[j]; ss += f[j] * f[j]; }
#pragma unroll
    for (int m = 1; m < 64; m <<= 1) { sum += __shfl_xor(sum, m, 64); ss += __shfl_xor(ss, m, 64); }
    __shared__ float red[8];
    int w = tid >> 6, l = tid & 63;
    if (l == 0) { red[w] = sum; red[4 + w] = ss; }
    __syncthreads();
    sum = red[0] + red[1] + red[2] + red[3];
    ss  = red[4] + red[5] + red[6] + red[7];
    float mean = sum * (1.f / 2048.f);
    float var  = ss * (1.f / 2048.f) - mean * mean;
    float rstd = rsqrtf(var + 1e-5f);
    const f32x4* sp = (const f32x4*)(sc + tid * 8);
    const f32x4* bp = (const f32x4*)(sh + tid * 8);
    f32x4 s0 = sp[0], s1 = sp[1], b0 = bp[0], b1 = bp[1];
    short8 o;
#pragma unroll
    for (int j = 0; j < 4; j++) {
        o[j]     = (short)f2bf((f[j] - mean) * rstd * s0[j] + b0[j]);
        o[4 + j] = (short)f2bf((f[4 + j] - mean) * rstd * s1[j] + b1[j]);
    }
    *(short8*)(out + (size_t)row * 2048 + tid * 8) = o;
}

// ---------------- GEMM: C(MxN) = A(MxK) * BT(NxK), bf16, 128x128 tile, BK=64 ----------------
// Round-6 proven 2-barrier double-buffer control flow; 0-conflict chunk-XOR LDS swizzle;
// XCD-chunked bijective block swizzle (SHAREB: group blocks sharing the B panel, else A).
// EPI: 0 plain, 1 +bias+residual, 2 +bias+gelu ; OUTF f32 out ; RESBF residual bf16
// SPLITM: 0 normal; 1 col>>11 split into ACT buffers; 2 col>>11 split into 2048x2048
template<int EPI, int OUTF, int RESBF, int SPLITM, int SHAREB>
__global__ __launch_bounds__(256, 2) void gemm_bt2(
    const u16* __restrict__ A, const u16* __restrict__ BT, void* __restrict__ Cp,
    const float* __restrict__ bias, const void* __restrict__ res, int M, int N, int K)
{
    __shared__ u16 As[2][128 * 64];
    __shared__ u16 Bs[2][128 * 64];
    int tid = threadIdx.x, l = tid & 63, w = tid >> 6;

    // XCD-chunked bijective swizzle: blocks on one XCD get a contiguous wg range
    int nbx = gridDim.x, nby = gridDim.y;
    int nwg = nbx * nby;
    int orig = blockIdx.y * nbx + blockIdx.x;
    int nch = nwg >> 3;
    int wg = (orig & 7) * nch + (orig >> 3);
    int bx, by;
    if (SHAREB) { bx = wg / nby; by = wg % nby; }   // consecutive wg share B panel
    else        { by = wg / nbx; bx = wg % nbx; }   // consecutive wg share A panel

    int mbase = by * 128, nbase = bx * 128;
    const u16* Ag = A + (size_t)mbase * K;
    const u16* Bg = BT + (size_t)nbase * K;
    int NT = K >> 6;

    // stage one 128x64 K-tile; LDS chunk (r, chp) holds global chunk (r, chp ^ (r&7))
    auto stage = [&](const u16* G, u16* Ld, int t) {
#pragma unroll
        for (int g = 0; g < 4; g++) {
            int ci = g * 256 + tid;
            int r = ci >> 3, chp = ci & 7;
            int ch = chp ^ (r & 7);
            const u16* gp = G + (size_t)r * K + t * 64 + ch * 8;
            __builtin_amdgcn_global_load_lds((gas_ptr)gp, (las_ptr)(Ld + (g * 256 + w * 64) * 8), 16, 0, 0);
        }
    };

    f32x4 acc[4][4];
#pragma unroll
    for (int i = 0; i < 4; i++)
#pragma unroll
        for (int j = 0; j < 4; j++) acc[i][j] = (f32x4){0.f, 0.f, 0.f, 0.f};
    int wr = (w >> 1) * 64, wc = (w & 1) * 64;

    stage(Ag, As[0], 0); stage(Bg, Bs[0], 0);
    __syncthreads();
    int buf = 0;
    for (int t = 0; t < NT; ++t) {
        if (t + 1 < NT) { stage(Ag, As[buf ^ 1], t + 1); stage(Bg, Bs[buf ^ 1], t + 1); }
        short8 af[2][4], bfr[2][4];
#pragma unroll
        for (int ks = 0; ks < 2; ks++) {
            int c = ks * 4 + (l >> 4);
#pragma unroll
            for (int i = 0; i < 4; i++) {
                int ra = wr + i * 16 + (l & 15);
                af[ks][i] = *(const short8*)&As[buf][ra * 64 + ((c ^ (ra & 7)) << 3)];
                int rb = wc + i * 16 + (l & 15);
                bfr[ks][i] = *(const short8*)&Bs[buf][rb * 64 + ((c ^ (rb & 7)) << 3)];
            }
        }
        __builtin_amdgcn_s_setprio(1);
#pragma unroll
        for (int ks = 0; ks < 2; ks++)
#pragma unroll
            for (int mi = 0; mi < 4; mi++)
#pragma unroll
                for (int ni = 0; ni < 4; ni++)
                    acc[mi][ni] = mfma16(af[ks][mi], bfr[ks][ni], acc[mi][ni]);
        __builtin_amdgcn_s_setprio(0);
        __syncthreads();
        buf ^= 1;
    }

#pragma unroll
    for (int mi = 0; mi < 4; mi++) {
#pragma unroll
        for (int ni = 0; ni < 4; ni++) {
            int col = nbase + wc + ni * 16 + (l & 15);
            float bval = (EPI != 0) ? bias[col] : 0.f;
#pragma unroll
            for (int r = 0; r < 4; r++) {
                int row = mbase + wr + mi * 16 + (l >> 4) * 4 + r;
                float v = acc[mi][ni][r];
                if (EPI == 1) {
                    size_t ridx = (size_t)row * N + col;
                    float rv = RESBF ? bf2f(((const u16*)res)[ridx]) : ((const float*)res)[ridx];
                    v += bval + rv;
                }
                if (EPI == 2) {
                    v += bval;
                    float tt = tanhf(0.7978845608028654f * (v + 0.044715f * v * v * v));
                    v = 0.5f * v * (1.f + tt);
                }
                if (SPLITM == 1) {
                    ((u16*)Cp)[(size_t)(col >> 11) * 8388608ULL + (size_t)row * 2048 + (col & 2047)] = f2bf(v);
                } else if (SPLITM == 2) {
                    ((u16*)Cp)[(size_t)(col >> 11) * 4194304ULL + (size_t)row * 2048 + (col & 2047)] = f2bf(v);
                } else if (OUTF) {
                    ((float*)Cp)[(size_t)row * N + col] = v;
                } else {
                    ((u16*)Cp)[(size_t)row * N + col] = f2bf(v);
                }
            }
        }
    }
}

// ---------------- Causal flash attention: H=16, HD=128, S=2048 ----------------
// QBLK=128: 4 waves x 32 q-rows. KVBLK=64. V pre-transposed: VTg[(b*16+h)*128+d][key]
__global__ __launch_bounds__(256, 2) void attn_kernel(
    const u16* __restrict__ Q, const u16* __restrict__ Kp, const u16* __restrict__ VTg,
    u16* __restrict__ O)
{
    __shared__ u16 Ks[64 * 128];
    __shared__ u16 VT[128 * 64];
    __shared__ u16 Ps[4 * 2048];
    int tid = threadIdx.x, l = tid & 63, w = tid >> 6;
    int qtl = (int)gridDim.x - 1 - (int)blockIdx.x;
    int bh = blockIdx.y, b = bh >> 4, h = bh & 15;
    const float SCALE = 0.08838834764831845f;
    int qbase = qtl * 128;
    size_t bS = (size_t)b * 2048;
    const u16* vrow = VTg + (size_t)bh * 128 * 2048;

    short8 qf[2][4];
#pragma unroll
    for (int mg = 0; mg < 2; mg++) {
        int qrow = qbase + w * 32 + mg * 16 + (l & 15);
        const u16* qp = Q + (bS + qrow) * 2048 + h * 128 + (l >> 4) * 8;
#pragma unroll
        for (int ds = 0; ds < 4; ds++) qf[mg][ds] = *(const short8*)(qp + ds * 32);
    }
    float m_[2][4], l_[2][4];
    f32x4 o_[2][8];
#pragma unroll
    for (int mg = 0; mg < 2; mg++)
#pragma unroll
        for (int r = 0; r < 4; r++) { m_[mg][r] = -1e30f; l_[mg][r] = 0.f; }
#pragma unroll
    for (int mg = 0; mg < 2; mg++)
#pragma unroll
        for (int d = 0; d < 8; d++) o_[mg][d] = (f32x4){0.f, 0.f, 0.f, 0.f};

    int ktmax = 2 * qtl + 1;
    for (int kt = 0; kt <= ktmax; ++kt) {
        int kbase = kt * 64;
#pragma unroll
        for (int it = 0; it < 4; ++it) {
            int slot = it * 256 + tid;
            int key = slot >> 4, dseg = slot & 15;
            short8 kv = *(const short8*)(Kp + (bS + kbase + key) * 2048 + h * 128 + dseg * 8);
            int kidx = ((key * 256 + dseg * 16) ^ ((key & 7) << 4)) >> 1;
            *(short8*)&Ks[kidx] = kv;
            int d = slot >> 3, k8 = slot & 7;
            short8 vv = *(const short8*)(vrow + (size_t)d * 2048 + kbase + k8 * 8);
            int vidx = ((d * 128 + k8 * 16) ^ ((d & 7) << 4)) >> 1;
            *(short8*)&VT[vidx] = vv;
        }
        __syncthreads();

        f32x4 s[2][4];
#pragma unroll
        for (int mg = 0; mg < 2; mg++)
#pragma unroll
            for (int kg = 0; kg < 4; kg++) s[mg][kg] = (f32x4){0.f, 0.f, 0.f, 0.f};
        __builtin_amdgcn_s_setprio(1);
#pragma unroll
        for (int kg = 0; kg < 4; kg++) {
            int key0 = kg * 16 + (l & 15);
#pragma unroll
            for (int ds = 0; ds < 4; ds++) {
                int i0 = ((key0 * 256 + ds * 64 + (l >> 4) * 16) ^ ((key0 & 7) << 4)) >> 1;
                short8 kb = *(const short8*)&Ks[i0];
                s[0][kg] = mfma16(qf[0][ds], kb, s[0][kg]);
                s[1][kg] = mfma16(qf[1][ds], kb, s[1][kg]);
            }
        }
        __builtin_amdgcn_s_setprio(0);

        bool domask = (kbase + 63) > qbase;
        float alpha[2][4];
        u16* Pw = &Ps[w * 2048];
#pragma unroll
        for (int mg = 0; mg < 2; mg++) {
#pragma unroll
            for (int r = 0; r < 4; r++) {
                int qrow = qbase + w * 32 + mg * 16 + (l >> 4) * 4 + r;
                float aa[4];
#pragma unroll
                for (int kg = 0; kg < 4; kg++) {
                    float a = s[mg][kg][r] * SCALE;
                    if (domask && (kbase + kg * 16 + (l & 15)) > qrow) a = -1e30f;
                    aa[kg] = a;
                }
                float mx = fmaxf(fmaxf(aa[0], aa[1]), fmaxf(aa[2], aa[3]));
                mx = fmaxf(mx, __shfl_xor(mx, 1, 64));
                mx = fmaxf(mx, __shfl_xor(mx, 2, 64));
                mx = fmaxf(mx, __shfl_xor(mx, 4, 64));
                mx = fmaxf(mx, __shfl_xor(mx, 8, 64));
                float mn = fmaxf(m_[mg][r], mx);
                float al = __expf(m_[mg][r] - mn);
                m_[mg][r] = mn;
                float p[4], rs = 0.f;
#pragma unroll
                for (int kg = 0; kg < 4; kg++) { p[kg] = __expf(aa[kg] - mn); rs += p[kg]; }
                rs += __shfl_xor(rs, 1, 64);
                rs += __shfl_xor(rs, 2, 64);
                rs += __shfl_xor(rs, 4, 64);
                rs += __shfl_xor(rs, 8, 64);
                l_[mg][r] = l_[mg][r] * al + rs;
                alpha[mg][r] = al;
#pragma unroll
                for (int kg = 0; kg < 4; kg++) {
                    int col = kg * 16 + (l & 15);
                    int lp = ((l >> 4) * 4 + r) | (((col >> 3) & 3) << 4);
                    Pw[(mg * 2 + (col >> 5)) * 512 + lp * 8 + (col & 7)] = f2bf(p[kg]);
                }
            }
        }
#pragma unroll
        for (int mg = 0; mg < 2; mg++)
#pragma unroll
            for (int dblk = 0; dblk < 8; dblk++)
#pragma unroll
                for (int r = 0; r < 4; r++) o_[mg][dblk][r] *= alpha[mg][r];

        __builtin_amdgcn_s_setprio(1);
#pragma unroll
        for (int kk = 0; kk < 2; kk++) {
            short8 pa0 = *(const short8*)&Pw[(0 * 2 + kk) * 512 + l * 8];
            short8 pa1 = *(const short8*)&Pw[(1 * 2 + kk) * 512 + l * 8];
#pragma unroll
            for (int dblk = 0; dblk < 8; dblk++) {
                int d = dblk * 16 + (l & 15);
                int iv = ((d * 128 + kk * 64 + (l >> 4) * 16) ^ ((d & 7) << 4)) >> 1;
                short8 vb = *(const short8*)&VT[iv];
                o_[0][dblk] = mfma16(pa0, vb, o_[0][dblk]);
                o_[1][dblk] = mfma16(pa1, vb, o_[1][dblk]);
            }
        }
        __builtin_amdgcn_s_setprio(0);
        __syncthreads();
    }

#pragma unroll
    for (int mg = 0; mg < 2; mg++) {
#pragma unroll
        for (int dblk = 0; dblk < 8; dblk++) {
#pragma unroll
            for (int r = 0; r < 4; r++) {
                int qrow = qbase + w * 32 + mg * 16 + (l >> 4) * 4 + r;
                float v = o_[mg][dblk][r] / l_[mg][r];
                O[(bS + qrow) * 2048 + h * 128 + dblk * 16 + (l & 15)] = f2bf(v);
            }
        }
    }
}

extern "C" void kernel_launch(void* const* d_in, const int* in_sizes, int n_in,
                              void* d_out, int out_size, void* d_ws, size_t ws_size,
                              hipStream_t stream)
{
    const float* x    = (const float*)d_in[0];
    const float* ln1s = (const float*)d_in[1];
    const float* ln1b = (const float*)d_in[2];
    const float* Wq   = (const float*)d_in[3];
    const float* Wk   = (const float*)d_in[4];
    const float* Wv   = (const float*)d_in[5];
    const float* Wo   = (const float*)d_in[6];
    const float* bo   = (const float*)d_in[7];
    const float* ln2s = (const float*)d_in[8];
    const float* ln2b = (const float*)d_in[9];
    const float* W1   = (const float*)d_in[10];
    const float* b1   = (const float*)d_in[11];
    const float* W2   = (const float*)d_in[12];
    const float* b2   = (const float*)d_in[13];
    float* out = (float*)d_out;
    const size_t ACT = 8388608ULL;

    u16* ws16 = (u16*)d_ws;
    u16* xn   = ws16;
    u16* q    = ws16 + ACT;
    u16* k    = ws16 + 2 * ACT;
    u16* vT   = ws16 + 3 * ACT;
    u16* hbuf = ws16 + 2 * ACT;
    u16* wt   = ws16 + 6 * ACT;
    u16* x2   = q;
    (void)k;

    dim3 blk(256);
    transpose_kernel<<<dim3(32, 32), blk, 0, stream>>>(Wq, wt,                  2048, 2048);
    transpose_kernel<<<dim3(32, 32), blk, 0, stream>>>(Wk, wt + (ACT >> 1),     2048, 2048);
    transpose_kernel<<<dim3(32, 32), blk, 0, stream>>>(Wv, wt + ACT,            2048, 2048);
    transpose_kernel<<<dim3(32, 32), blk, 0, stream>>>(Wo, wt + 3 * (ACT >> 1), 2048, 2048);
    ln_kernel<0><<<4096, blk, 0, stream>>>(x, ln1s, ln1b, xn);
    // fused QK: BT = [WqT;WkT] -> q, k buffers
    gemm_bt2<0, 0, 0, 1, 1><<<dim3(32, 32), blk, 0, stream>>>(xn, wt, q, nullptr, nullptr, 4096, 4096, 2048);
    // vT = WvT * xn^T -> vT[b][d][s]
    gemm_bt2<0, 0, 0, 2, 1><<<dim3(32, 16), blk, 0, stream>>>(wt + ACT, xn, vT, nullptr, nullptr, 2048, 4096, 2048);
    attn_kernel<<<dim3(16, 32), blk, 0, stream>>>(q, k, vT, xn); // ctx -> xn
    gemm_bt2<1, 0, 0, 0, 0><<<dim3(16, 32), blk, 0, stream>>>(xn, wt + 3 * (ACT >> 1), x2, bo, x, 4096, 2048, 2048);
    transpose_kernel<<<dim3(128, 32), blk, 0, stream>>>(W1, wt, 2048, 8192);
    ln_kernel<1><<<4096, blk, 0, stream>>>(x2, ln2s, ln2b, xn);
    gemm_bt2<2, 0, 0, 0, 1><<<dim3(64, 32), blk, 0, stream>>>(xn, wt, hbuf, b1, nullptr, 4096, 8192, 2048);
    transpose_kernel<<<dim3(32, 128), blk, 0, stream>>>(W2, wt, 8192, 2048);
    gemm_bt2<1, 1, 1, 0, 0><<<dim3(16, 32), blk, 0, stream>>>(hbuf, wt, out, b2, x2, 4096, 2048, 8192);
}